// Round 1
// baseline (205.055 us; speedup 1.0000x reference)
//
#include <hip/hip_runtime.h>
#include <hip/hip_bf16.h>

#define B_N    16
#define C_IN   64
#define HW_IN  48
#define PH     50
#define NJ     9
#define QDIM   576
#define OC     128
#define M_TOT  36864
#define NKT    81
#define PHI_PLANE 2500   // 50*50

typedef __attribute__((ext_vector_type(8))) short short8;
typedef __attribute__((ext_vector_type(4))) float floatx4;

__device__ __forceinline__ unsigned short f2bf(float f) {
    union { float f; unsigned u; } v; v.f = f;
    unsigned r = (v.u + 0x7FFFu + ((v.u >> 16) & 1u)) >> 16;
    return (unsigned short)r;
}

// phi[0] = silu(x); phi[1..8] = cubic B-spline bases on uniform grid [-2.2 .. 2.2], h=0.4
__device__ __forceinline__ void compute_phi(float x, float* phi) {
    phi[0] = x / (1.0f + __expf(-x));
    float t[12];
#pragma unroll
    for (int i = 0; i < 12; ++i) t[i] = 0.4f * (float)(i - 3) - 1.0f;
    float bb[11];
#pragma unroll
    for (int j = 0; j < 11; ++j) bb[j] = (x >= t[j] && x < t[j + 1]) ? 1.0f : 0.0f;
#pragma unroll
    for (int k = 1; k <= 3; ++k) {
#pragma unroll
        for (int j = 0; j + k < 11; ++j) {
            float left  = (x - t[j]) / (t[j + k] - t[j]) * bb[j];
            float right = (t[j + k + 1] - x) / (t[j + k + 1] - t[j + 1]) * bb[j + 1];
            bb[j] = left + right;
        }
    }
#pragma unroll
    for (int g = 0; g < 8; ++g) phi[1 + g] = bb[g];
}

// Pass 1: Phi[b][c][j][hh][ww] (padded 50x50), bf16. One block per (b,c).
__global__ __launch_bounds__(256) void phi_kernel(const float* __restrict__ x,
                                                  unsigned short* __restrict__ Phi) {
    int bc = blockIdx.x;  // b*64 + c
    const float* xsrc = x + (size_t)bc * (HW_IN * HW_IN);
    unsigned short* pdst = Phi + (size_t)bc * NJ * PHI_PLANE;
    for (int p = threadIdx.x; p < PHI_PLANE; p += 256) {
        int hh = p / 50, ww = p % 50;
        float xv = 0.0f;
        if (hh >= 1 && hh <= 48 && ww >= 1 && ww <= 48)
            xv = xsrc[(hh - 1) * 48 + (ww - 1)];
        float phi[9];
        compute_phi(xv, phi);
#pragma unroll
        for (int j = 0; j < 9; ++j) pdst[(size_t)j * PHI_PLANE + p] = f2bf(phi[j]);
    }
}

// Pass 0: pack weights into Wp, per 64-k tile [oc=128][kk=64] bf16, XOR-swizzled.
// k = j*576 + q  (j=0: base_weight; j=1..8: spline_weight*scaler). tile kt = j*9 + q/64, kk=q%64.
__global__ __launch_bounds__(256) void pack_kernel(const float* __restrict__ bw,
                                                   const float* __restrict__ sw,
                                                   const float* __restrict__ sc,
                                                   unsigned short* __restrict__ Wp) {
    int gtid = blockIdx.x * 256 + threadIdx.x;  // oc*576 + q ; 73728 total
    int oc = gtid / QDIM, q = gtid % QDIM;
    float base = bw[gtid];
    float scal = sc[gtid];
    unsigned char* wp8 = (unsigned char*)Wp;
    int off_oq = (oc * 128 + (q & 63) * 2) ^ ((oc & 7) << 4);
    int ktb = q >> 6;
    *(unsigned short*)(wp8 + (size_t)ktb * 16384 + off_oq) = f2bf(base);
#pragma unroll
    for (int g = 0; g < 8; ++g) {
        float v = sw[(size_t)gtid * 8 + g] * scal;
        *(unsigned short*)(wp8 + (size_t)((g + 1) * 9 + ktb) * 16384 + off_oq) = f2bf(v);
    }
}

// GEMM: out[n][oc] = sum_k A[n][k]*W[k][oc].  M=36864, N=128, K=5184.
// Tile: BM=64 (n), BN=128 (oc), BK=64.  4 waves: each 32m x 64oc, acc[2][4].
__global__ __launch_bounds__(256, 3) void gemm_kernel(const unsigned short* __restrict__ Phi,
                                                      const unsigned short* __restrict__ Wp,
                                                      float* __restrict__ out) {
    __shared__ __align__(16) unsigned char lds[49152]; // W dbuf 2x16K @0, Phi dbuf 2x8K @32768
    int bid = blockIdx.x;
    int swzb = (bid & 7) * 72 + (bid >> 3);   // XCD-bijective (576 = 8*72)
    int m0 = swzb * 64;
    int tid = threadIdx.x;
    int lane = tid & 63;
    int wv = tid >> 6;
    int wm2 = wv & 1, wo2 = wv >> 1;
    int lo = lane & 15, hi = lane >> 4;

    // ---- staging precompute: this thread stages Phi rows r0 and r0+32 (8 lanes/row) ----
    int s8 = tid & 7;
    int r0 = tid >> 3;            // 0..31
    int sx = s8 ^ (r0 & 7);       // swizzled chunk slot -> logical chunk loaded
    size_t rowbase[2];
#pragma unroll
    for (int i = 0; i < 2; ++i) {
        int n  = m0 + r0 + 32 * i;
        int b  = n / 2304;
        int u  = n % 2304;
        int du = u >> 2;          // patches feature index (c,kh,kw)
        int r  = u & 3;           // 576-chunk within the reinterpreted row
        int c  = du / 9;
        int tap = du % 9;
        int kh = tap / 3, kw = tap % 3;
        rowbase[i] = ((size_t)(b * C_IN + c) * NJ) * PHI_PLANE
                   + (size_t)((r * 12 + kh) * 50 + kw);
    }

    auto stage = [&](int sel, int kt) {
        int j  = kt / 9;
        int q0 = (kt % 9) << 6;
        int qs = q0 + sx * 8;           // logical q of this lane's 16B chunk
        int hq = qs / 48, wq = qs % 48; // never crosses the 48-wrap inside a chunk
        size_t delta = (size_t)j * PHI_PLANE + (size_t)(hq * 50 + wq);
        unsigned char* pb = lds + 32768 + sel * 8192;
        const unsigned short* s0 = Phi + rowbase[0] + delta;
        const unsigned short* s1 = Phi + rowbase[1] + delta;
        __builtin_amdgcn_global_load_lds((const __attribute__((address_space(1))) void*)s0,
                                         (__attribute__((address_space(3))) void*)(pb + tid * 16), 16, 0, 0);
        __builtin_amdgcn_global_load_lds((const __attribute__((address_space(1))) void*)s1,
                                         (__attribute__((address_space(3))) void*)(pb + 4096 + tid * 16), 16, 0, 0);
        const unsigned char* ws = (const unsigned char*)Wp + (size_t)kt * 16384;
        unsigned char* wb = lds + sel * 16384;
#pragma unroll
        for (int i = 0; i < 4; ++i)
            __builtin_amdgcn_global_load_lds((const __attribute__((address_space(1))) void*)(ws + i * 4096 + tid * 16),
                                             (__attribute__((address_space(3))) void*)(wb + i * 4096 + tid * 16), 16, 0, 0);
    };

    floatx4 acc[2][4];
    floatx4 zz = {0.f, 0.f, 0.f, 0.f};
#pragma unroll
    for (int a = 0; a < 2; ++a)
#pragma unroll
        for (int b = 0; b < 4; ++b) acc[a][b] = zz;

    int abase[2], bbase[4];
#pragma unroll
    for (int fm = 0; fm < 2; ++fm) abase[fm] = (wm2 * 32 + fm * 16 + lo) * 128;
#pragma unroll
    for (int fo = 0; fo < 4; ++fo) bbase[fo] = (wo2 * 64 + fo * 16 + lo) * 128;
    int l7 = lane & 7;

    auto compute = [&](int sel) {
        const unsigned char* wb = lds + sel * 16384;
        const unsigned char* pb = lds + 32768 + sel * 8192;
#pragma unroll
        for (int ks = 0; ks < 2; ++ks) {
            int ch = ((ks * 4 + hi) ^ l7) * 16;
            short8 af[2], bf[4];
#pragma unroll
            for (int fm = 0; fm < 2; ++fm) af[fm] = *(const short8*)(pb + abase[fm] + ch);
#pragma unroll
            for (int fo = 0; fo < 4; ++fo) bf[fo] = *(const short8*)(wb + bbase[fo] + ch);
#pragma unroll
            for (int fm = 0; fm < 2; ++fm)
#pragma unroll
                for (int fo = 0; fo < 4; ++fo)
                    acc[fm][fo] = __builtin_amdgcn_mfma_f32_16x16x32_bf16(af[fm], bf[fo], acc[fm][fo], 0, 0, 0);
        }
    };

    stage(0, 0);
    __syncthreads();
#pragma unroll 2
    for (int kt = 0; kt < NKT; ++kt) {
        if (kt + 1 < NKT) stage((kt + 1) & 1, kt + 1);
        compute(kt & 1);
        __syncthreads();
    }

    // Epilogue: D[m][oc], m=row((lane>>4)*4+reg), oc=col(lane&15). out flat = n*128 + oc.
#pragma unroll
    for (int fm = 0; fm < 2; ++fm) {
        int nrow = m0 + wm2 * 32 + fm * 16 + hi * 4;
#pragma unroll
        for (int fo = 0; fo < 4; ++fo) {
            int oc = wo2 * 64 + fo * 16 + lo;
            float* op = out + (size_t)nrow * 128 + oc;
#pragma unroll
            for (int r = 0; r < 4; ++r)
                op[(size_t)r * 128] = acc[fm][fo][r];
        }
    }
}

extern "C" void kernel_launch(void* const* d_in, const int* in_sizes, int n_in,
                              void* d_out, int out_size, void* d_ws, size_t ws_size,
                              hipStream_t stream) {
    const float* x  = (const float*)d_in[0];
    const float* bw = (const float*)d_in[1];
    const float* sw = (const float*)d_in[2];
    const float* sc = (const float*)d_in[3];
    float* out = (float*)d_out;

    unsigned short* Wp  = (unsigned short*)d_ws;                          // 81*16384 = 1.33 MB
    unsigned short* Phi = (unsigned short*)((char*)d_ws + (2u << 20));    // 46.08 MB

    pack_kernel<<<288, 256, 0, stream>>>(bw, sw, sc, Wp);
    phi_kernel<<<B_N * C_IN, 256, 0, stream>>>(x, Phi);
    gemm_kernel<<<M_TOT / 64, 256, 0, stream>>>(Phi, Wp, out);
}

// Round 2
// 149.628 us; speedup vs baseline: 1.3704x; 1.3704x over previous
//
#include <hip/hip_runtime.h>
#include <hip/hip_bf16.h>

#define B_N    16
#define C_IN   64
#define QDIM   576
#define OC     128
#define M_TOT  36864
#define NKT    81
#define PLANE  2512   // 50*50 = 2500 padded to multiple of 8 for 16B stores

typedef __attribute__((ext_vector_type(8))) short short8;
typedef __attribute__((ext_vector_type(4))) float floatx4;

__device__ __forceinline__ unsigned short f2bf(float f) {
    union { float f; unsigned u; } v; v.f = f;
    unsigned r = (v.u + 0x7FFFu + ((v.u >> 16) & 1u)) >> 16;
    return (unsigned short)r;
}

// phi[0] = silu(x); phi[1..8] = cubic B-spline bases on uniform grid [-2.2..2.2], h=0.4.
// Uniform grid -> Cox-de Boor denominators are k*h; use exact reciprocal constants 2.5/k.
__device__ __forceinline__ void compute_phi(float x, float* phi) {
    phi[0] = x * __builtin_amdgcn_rcpf(1.0f + __expf(-x));
    float t[12];
#pragma unroll
    for (int i = 0; i < 12; ++i) t[i] = 0.4f * (float)(i - 3) - 1.0f;
    float bb[11];
#pragma unroll
    for (int j = 0; j < 11; ++j) bb[j] = (x >= t[j] && x < t[j + 1]) ? 1.0f : 0.0f;
#pragma unroll
    for (int j = 0; j < 10; ++j)
        bb[j] = (x - t[j]) * 2.5f * bb[j] + (t[j + 2] - x) * 2.5f * bb[j + 1];
#pragma unroll
    for (int j = 0; j < 9; ++j)
        bb[j] = (x - t[j]) * 1.25f * bb[j] + (t[j + 3] - x) * 1.25f * bb[j + 1];
#pragma unroll
    for (int j = 0; j < 8; ++j)
        bb[j] = (x - t[j]) * (2.5f / 3.0f) * bb[j] + (t[j + 4] - x) * (2.5f / 3.0f) * bb[j + 1];
#pragma unroll
    for (int g = 0; g < 8; ++g) phi[1 + g] = bb[g];
}

// Pass 1: Phi[b][c][j][2512], padded 50x50 plane. 8 pixels/thread, short8 stores.
__global__ __launch_bounds__(256) void phi_kernel(const float* __restrict__ x,
                                                  unsigned short* __restrict__ Phi) {
    int ch = blockIdx.x * 256 + threadIdx.x;   // 1024 bc * 314 chunks = 321536
    int bc = ch / 314;
    int cp = ch - bc * 314;
    int p0 = cp * 8;
    const float* xsrc = x + (size_t)bc * 2304;
    short8 v[9];
#pragma unroll
    for (int e = 0; e < 8; ++e) {
        int p = p0 + e;
        int hh = p / 50;
        int ww = p - hh * 50;
        float xv = (hh >= 1 && hh <= 48 && ww >= 1 && ww <= 48) ? xsrc[(hh - 1) * 48 + (ww - 1)] : 0.0f;
        float phi[9];
        compute_phi(xv, phi);
#pragma unroll
        for (int j = 0; j < 9; ++j) v[j][e] = (short)f2bf(phi[j]);
    }
    unsigned short* pdst = Phi + (size_t)bc * 9 * PLANE + p0;
#pragma unroll
    for (int j = 0; j < 9; ++j) *(short8*)(pdst + (size_t)j * PLANE) = v[j];
}

// Pass 0: pack weights, per 64-k tile [oc=128][kk=64] bf16, XOR-swizzled (bits 4..6 ^ oc&7).
__global__ __launch_bounds__(256) void pack_kernel(const float* __restrict__ bw,
                                                   const float* __restrict__ sw,
                                                   const float* __restrict__ sc,
                                                   unsigned short* __restrict__ Wp) {
    int gtid = blockIdx.x * 256 + threadIdx.x;  // oc*576 + q ; 73728 total
    int oc = gtid / QDIM, q = gtid % QDIM;
    float base = bw[gtid];
    float scal = sc[gtid];
    unsigned char* wp8 = (unsigned char*)Wp;
    int off_oq = (oc * 128 + (q & 63) * 2) ^ ((oc & 7) << 4);
    int ktb = q >> 6;
    *(unsigned short*)(wp8 + (size_t)ktb * 16384 + off_oq) = f2bf(base);
#pragma unroll
    for (int g = 0; g < 8; ++g) {
        float v = sw[(size_t)gtid * 8 + g] * scal;
        *(unsigned short*)(wp8 + (size_t)((g + 1) * 9 + ktb) * 16384 + off_oq) = f2bf(v);
    }
}

// GEMM: out[n][oc] = sum_k A[n][k]*W[k][oc].  M=36864, N=128, K=5184.
// Tile BM=48, BN=128, BK=64. grid=768 = exactly 3 blocks/CU.
// 4 waves = (wo in 0..1 oc-half) x (wk in 0..1 k-half); wave tile 48m x 64oc x 32k, acc[3][4].
// K-halves reduced through LDS in epilogue.
__global__ __launch_bounds__(256, 3) void gemm_kernel(const unsigned short* __restrict__ Phi,
                                                      const unsigned short* __restrict__ Wp,
                                                      float* __restrict__ out) {
    __shared__ __align__(16) unsigned char lds[45056]; // W dbuf 2x16K @0, Phi dbuf 2x6K @32768
    int bid = blockIdx.x;
    int swzb = (bid & 7) * 96 + (bid >> 3);   // XCD-bijective (768 = 8*96)
    int m0 = swzb * 48;
    int tid = threadIdx.x;
    int lane = tid & 63;
    int wv = tid >> 6;
    int wo = wv & 1, wk = wv >> 1;
    int lo = lane & 15, hi = lane >> 4, l7 = lane & 7;

    // staging: pass A = chunks 0..255 (rows 0..31), pass B = chunks 256..383 (rows 32..47, tid<128)
    int s8 = tid & 7;
    int rA = tid >> 3;
    int sxA = s8 ^ (rA & 7);
    int rB = (tid < 128) ? (32 + (tid >> 3)) : rA;
    int sxB = s8 ^ (rB & 7);

    size_t rowb[2];
    int rows[2] = {rA, rB};
#pragma unroll
    for (int i = 0; i < 2; ++i) {
        int n  = m0 + rows[i];
        int b  = n / 2304;
        int u  = n - b * 2304;
        int du = u >> 2;          // patches feature (c,kh,kw)
        int r  = u & 3;           // 576-chunk within reinterpreted row
        int c  = du / 9;
        int tap = du - c * 9;
        int kh = tap / 3, kw = tap - kh * 3;
        rowb[i] = ((size_t)(b * C_IN + c) * 9) * PLANE + (size_t)((r * 12 + kh) * 50 + kw);
    }

    auto stage = [&](int sel, int kt) {
        int j  = kt / 9;
        int q0 = (kt - j * 9) << 6;
        unsigned char* pb = lds + 32768 + sel * 6144;
        {
            int qs = q0 + sxA * 8;
            int hq = qs / 48, wq = qs - hq * 48;   // 16B chunk never crosses 48-wrap
            const unsigned short* src = Phi + rowb[0] + (size_t)j * PLANE + (size_t)(hq * 50 + wq);
            __builtin_amdgcn_global_load_lds((const __attribute__((address_space(1))) void*)src,
                                             (__attribute__((address_space(3))) void*)(pb + tid * 16), 16, 0, 0);
        }
        if (tid < 128) {
            int qs = q0 + sxB * 8;
            int hq = qs / 48, wq = qs - hq * 48;
            const unsigned short* src = Phi + rowb[1] + (size_t)j * PLANE + (size_t)(hq * 50 + wq);
            __builtin_amdgcn_global_load_lds((const __attribute__((address_space(1))) void*)src,
                                             (__attribute__((address_space(3))) void*)(pb + 4096 + tid * 16), 16, 0, 0);
        }
        const unsigned char* ws = (const unsigned char*)Wp + (size_t)kt * 16384;
        unsigned char* wb = lds + sel * 16384;
#pragma unroll
        for (int i = 0; i < 4; ++i)
            __builtin_amdgcn_global_load_lds((const __attribute__((address_space(1))) void*)(ws + i * 4096 + tid * 16),
                                             (__attribute__((address_space(3))) void*)(wb + i * 4096 + tid * 16), 16, 0, 0);
    };

    floatx4 acc[3][4];
    floatx4 zz = {0.f, 0.f, 0.f, 0.f};
#pragma unroll
    for (int a = 0; a < 3; ++a)
#pragma unroll
        for (int b = 0; b < 4; ++b) acc[a][b] = zz;

    int sxr = ((wk * 4 + hi) ^ l7) << 4;   // swizzled chunk-slot byte offset (A and B share it)
    int arow[3], brow[4];
#pragma unroll
    for (int fm = 0; fm < 3; ++fm) arow[fm] = (fm * 16 + lo) * 128;
#pragma unroll
    for (int fo = 0; fo < 4; ++fo) brow[fo] = (wo * 64 + fo * 16 + lo) * 128;

    auto compute = [&](int sel) {
        const unsigned char* wb = lds + sel * 16384;
        const unsigned char* pb = lds + 32768 + sel * 6144;
        short8 af[3], bf[4];
#pragma unroll
        for (int fm = 0; fm < 3; ++fm) af[fm] = *(const short8*)(pb + arow[fm] + sxr);
#pragma unroll
        for (int fo = 0; fo < 4; ++fo) bf[fo] = *(const short8*)(wb + brow[fo] + sxr);
#pragma unroll
        for (int fm = 0; fm < 3; ++fm)
#pragma unroll
            for (int fo = 0; fo < 4; ++fo)
                acc[fm][fo] = __builtin_amdgcn_mfma_f32_16x16x32_bf16(af[fm], bf[fo], acc[fm][fo], 0, 0, 0);
    };

    stage(0, 0);
    __syncthreads();
#pragma unroll 2
    for (int kt = 0; kt < NKT; ++kt) {
        if (kt + 1 < NKT) stage((kt + 1) & 1, kt + 1);
        compute(kt & 1);
        __syncthreads();
    }

    // Epilogue: reduce k-halves via LDS (f32 [2][48][65]), then store.
    float* red = (float*)lds;
    if (wk == 1) {
#pragma unroll
        for (int fm = 0; fm < 3; ++fm)
#pragma unroll
            for (int fo = 0; fo < 4; ++fo)
#pragma unroll
                for (int r = 0; r < 4; ++r)
                    red[(wo * 48 + fm * 16 + hi * 4 + r) * 65 + fo * 16 + lo] = acc[fm][fo][r];
    }
    __syncthreads();
    if (wk == 0) {
#pragma unroll
        for (int fm = 0; fm < 3; ++fm) {
#pragma unroll
            for (int fo = 0; fo < 4; ++fo) {
                int oc = wo * 64 + fo * 16 + lo;
#pragma unroll
                for (int r = 0; r < 4; ++r) {
                    int nrow = m0 + fm * 16 + hi * 4 + r;
                    out[(size_t)nrow * 128 + oc] =
                        acc[fm][fo][r] + red[(wo * 48 + fm * 16 + hi * 4 + r) * 65 + fo * 16 + lo];
                }
            }
        }
    }
}

extern "C" void kernel_launch(void* const* d_in, const int* in_sizes, int n_in,
                              void* d_out, int out_size, void* d_ws, size_t ws_size,
                              hipStream_t stream) {
    const float* x  = (const float*)d_in[0];
    const float* bw = (const float*)d_in[1];
    const float* sw = (const float*)d_in[2];
    const float* sc = (const float*)d_in[3];
    float* out = (float*)d_out;

    unsigned short* Wp  = (unsigned short*)d_ws;                        // 81*16384 = 1.33 MB
    unsigned short* Phi = (unsigned short*)((char*)d_ws + 1572864);     // 1024*9*2512*2 = 46.3 MB

    pack_kernel<<<288, 256, 0, stream>>>(bw, sw, sc, Wp);
    phi_kernel<<<1256, 256, 0, stream>>>(x, Phi);
    gemm_kernel<<<M_TOT / 48, 256, 0, stream>>>(Phi, Wp, out);
}